// Round 6
// baseline (261.118 us; speedup 1.0000x reference)
//
#include <hip/hip_runtime.h>
#include <hip/hip_bf16.h>
#include <stdint.h>

typedef unsigned short u16;
typedef __attribute__((ext_vector_type(4))) float f32x4;
typedef __attribute__((ext_vector_type(8))) __bf16 bf16x8;
typedef __attribute__((ext_vector_type(8))) unsigned short u16x8;

#define NB 2
#define NT 2048
#define NC 2048
#define NH 16
#define NKV 4
#define HD 128
#define NQKV 3072
#define NQT 32   // NT/64
#define SCALE2 0.12751739f  // (1/sqrt(128)) * log2(e)

__device__ __forceinline__ u16 f2bf(float f) {
  union { float f; uint32_t u; } c; c.f = f;
  uint32_t u = c.u + 0x7fffu + ((c.u >> 16) & 1u);
  return (u16)(u >> 16);
}
__device__ __forceinline__ float bf2f(u16 h) {
  union { uint32_t u; float f; } c; c.u = ((uint32_t)h) << 16;
  return c.f;
}
__device__ __forceinline__ uint32_t packbf2(float a, float b) {
  return (uint32_t)f2bf(a) | ((uint32_t)f2bf(b) << 16);
}

// global -> LDS async copy, 16B per lane. LDS dest = wave-uniform base + lane*16.
__device__ __forceinline__ void gload16(const void* g, void* lds) {
  __builtin_amdgcn_global_load_lds(
      (__attribute__((address_space(1))) void*)(uintptr_t)g,
      (__attribute__((address_space(3))) void*)(uint32_t)(uintptr_t)lds,
      16, 0, 0);
}

// ---------------- fp32 -> bf16 convert (plain) ----------------
__global__ void cvt_bf16_kernel(const float* __restrict__ in, u16* __restrict__ out, int n4) {
  int i = blockIdx.x * blockDim.x + threadIdx.x;
  if (i >= n4) return;
  float4 v = ((const float4*)in)[i];
  uint32_t lo = (uint32_t)f2bf(v.x) | ((uint32_t)f2bf(v.y) << 16);
  uint32_t hi = (uint32_t)f2bf(v.z) | ((uint32_t)f2bf(v.w) << 16);
  ((uint2*)out)[i] = make_uint2(lo, hi);
}

// ---------------- fp32 -> bf16 convert with Q/K-head row permutation ----------------
// Row permutation puts RoPE pair (f, f+64) at adjacent col-16 blocks (c, c+16) so the
// GEMM epilogue holds both halves in-register. c -> feat: q=c>>5, e=c&15, hi=(c>>4)&1;
// feat = q*16 + e + hi*64. V heads (hh>=20) unpermuted.
__global__ void cvt_wqkv_kernel(const float* __restrict__ in, u16* __restrict__ out, int n4) {
  int i = blockIdx.x * blockDim.x + threadIdx.x;
  if (i >= n4) return;
  int row_new = i >> 9;            // NC/4 = 512 groups per row
  int col4 = (i & 511) * 4;
  int hh = row_new >> 7;
  int row_old = row_new;
  if (hh < NH + NKV) {
    int c = row_new & 127;
    int feat = (((c >> 5) << 4)) + (c & 15) + (((c >> 4) & 1) << 6);
    row_old = (hh << 7) + feat;
  }
  float4 v = *(const float4*)(in + (long)row_old * NC + col4);
  uint32_t lo = (uint32_t)f2bf(v.x) | ((uint32_t)f2bf(v.y) << 16);
  uint32_t hi = (uint32_t)f2bf(v.z) | ((uint32_t)f2bf(v.w) << 16);
  *(uint2*)(out + (long)row_new * NC + col4) = make_uint2(lo, hi);
}

// ---------------- RoPE cos/sin table ----------------
__global__ void rope_tab_kernel(float* __restrict__ tab) {
  int idx = blockIdx.x * blockDim.x + threadIdx.x;  // NT*64
  int t = idx >> 6, i = idx & 63;
  float inv = expf(-(float)(2 * i) * (9.210340371976184f / 128.f));
  float f = (float)t * inv;
  tab[t * 128 + i] = cosf(f);
  tab[t * 128 + 64 + i] = sinf(f);
}

// ---------------- V transpose: Vc[bt][512] -> Vt[b][kh][d][t] ----------------
__global__ void vtrans_kernel(const u16* __restrict__ Vc, u16* __restrict__ Vt) {
  __shared__ u16 tile[64][72];
  const int t0 = (blockIdx.x >> 1) * 64;
  const int d0 = (blockIdx.x & 1) * 64;
  const int bkh = blockIdx.y;                 // b*NKV + kh
  const int tid = threadIdx.x;
  const int tr = tid >> 2;
  const int tc = (tid & 3) * 16;
  const u16* src = Vc + ((long)((bkh >> 2) * NT) + t0 + tr) * (NKV * HD) +
                   (bkh & 3) * HD + d0 + tc;
  uint4 v0 = *(const uint4*)(src);
  uint4 v1 = *(const uint4*)(src + 8);
  *(uint4*)&tile[tr][tc] = v0;
  *(uint4*)&tile[tr][tc + 8] = v1;
  __syncthreads();
  const int dr = tid >> 2;
  const int tcc = (tid & 3) * 16;
  uint32_t pk[8];
#pragma unroll
  for (int e = 0; e < 8; ++e) {
    u16 a = tile[tcc + 2 * e][dr];
    u16 bq = tile[tcc + 2 * e + 1][dr];
    pk[e] = (uint32_t)a | ((uint32_t)bq << 16);
  }
  u16* dst = Vt + ((long)bkh * HD + d0 + dr) * NT + t0 + tcc;
  *(uint4*)(dst) = *(uint4*)&pk[0];
  *(uint4*)(dst + 8) = *(uint4*)&pk[4];
}

// ---------------- GEMM: C[M][N] = A[M][K] * B[N][K]^T ----------------
// MODE 0: write f32 C.  MODE 1: fused QKV epilogue (RoPE in-register via the
// permuted-B trick; Q pre-scaled by SCALE2; V to compact Vc).
template <int MODE>
__global__ __launch_bounds__(256) void gemm_bt_kernel(const u16* __restrict__ A,
                                                      const u16* __restrict__ Bm,
                                                      void* __restrict__ Cm,
                                                      int M, int N, int K,
                                                      const float* __restrict__ tab,
                                                      u16* __restrict__ Qp,
                                                      u16* __restrict__ Kp,
                                                      u16* __restrict__ Vcp) {
  __shared__ __align__(16) u16 As[128 * 32];
  __shared__ __align__(16) u16 Bs[128 * 32];
  const int tid = threadIdx.x;
  const int lane = tid & 63;
  const int wid = tid >> 6;
  const long row0 = (long)blockIdx.y * 128;
  const long col0 = (long)blockIdx.x * 128;
  const int wr = (wid >> 1) * 64;
  const int wc = (wid & 1) * 64;
  const int g = lane >> 4;
  const int r = lane & 15;
  const int crow = lane >> 2;
  const int ccol = (lane & 3) * 8;
  const int c0 = wid * 2, c1 = wid * 2 + 1;

  f32x4 acc[4][4] = {};

  const u16* Abase0 = A + (row0 + c0 * 16 + crow) * (long)K + ccol;
  const u16* Abase1 = A + (row0 + c1 * 16 + crow) * (long)K + ccol;
  const u16* Bbase0 = Bm + (col0 + c0 * 16 + crow) * (long)K + ccol;
  const u16* Bbase1 = Bm + (col0 + c1 * 16 + crow) * (long)K + ccol;

  for (int k0 = 0; k0 < K; k0 += 32) {
    gload16(Abase0 + k0, &As[c0 * 512]);
    gload16(Abase1 + k0, &As[c1 * 512]);
    gload16(Bbase0 + k0, &Bs[c0 * 512]);
    gload16(Bbase1 + k0, &Bs[c1 * 512]);
    __syncthreads();
    bf16x8 af[4], bfr[4];
#pragma unroll
    for (int mi = 0; mi < 4; ++mi)
      af[mi] = *(const bf16x8*)&As[(wr + mi * 16 + r) * 32 + 8 * g];
#pragma unroll
    for (int ni = 0; ni < 4; ++ni)
      bfr[ni] = *(const bf16x8*)&Bs[(wc + ni * 16 + r) * 32 + 8 * g];
#pragma unroll
    for (int mi = 0; mi < 4; ++mi)
#pragma unroll
      for (int ni = 0; ni < 4; ++ni)
        acc[mi][ni] = __builtin_amdgcn_mfma_f32_16x16x32_bf16(af[mi], bfr[ni], acc[mi][ni], 0, 0, 0);
    __syncthreads();
  }

  if (MODE == 0) {
#pragma unroll
    for (int mi = 0; mi < 4; ++mi)
#pragma unroll
      for (int ni = 0; ni < 4; ++ni)
#pragma unroll
        for (int j = 0; j < 4; ++j) {
          long rr = row0 + wr + mi * 16 + g * 4 + j;
          long cc = col0 + wc + ni * 16 + r;
          ((float*)Cm)[rr * N + cc] = acc[mi][ni][j];
        }
  } else {
    const int hh = (int)(col0 >> 7);   // block == one head (N-tile 128 == HD)
    if (hh < NH + NKV) {
      const bool isQ = (hh < NH);
#pragma unroll
      for (int mi = 0; mi < 4; ++mi)
#pragma unroll
        for (int nip = 0; nip < 2; ++nip) {
          const int ni = nip * 2;
          const int f = (((wc + ni * 16) >> 5) << 4) + r;  // feat in [0,64)
#pragma unroll
          for (int j = 0; j < 4; ++j) {
            long rr = row0 + wr + mi * 16 + g * 4 + j;
            int t = (int)(rr & (NT - 1));
            int b = (int)(rr >> 11);
            float cv = tab[t * 128 + f];
            float sv = tab[t * 128 + 64 + f];
            float x0 = acc[mi][ni][j], x1 = acc[mi][ni + 1][j];
            float lo = x0 * cv - x1 * sv;
            float hi = x1 * cv + x0 * sv;
            u16* dst;
            if (isQ) {
              lo *= SCALE2; hi *= SCALE2;
              dst = Qp + ((long)(b * NH + hh) * NT + t) * HD;
            } else {
              dst = Kp + ((long)(b * NKV + (hh - NH)) * NT + t) * HD;
            }
            dst[f] = f2bf(lo);
            dst[f + 64] = f2bf(hi);
          }
        }
    } else {
      const int vh = hh - NH - NKV;
#pragma unroll
      for (int mi = 0; mi < 4; ++mi)
#pragma unroll
        for (int ni = 0; ni < 4; ++ni)
#pragma unroll
          for (int j = 0; j < 4; ++j) {
            long rr = row0 + wr + mi * 16 + g * 4 + j;
            int c = wc + ni * 16 + r;
            Vcp[rr * (NKV * HD) + vh * HD + c] = f2bf(acc[mi][ni][j]);
          }
    }
  }
}

// ---------------- Flash attention v5: shfl-free steady state ----------------
// Grid: (NQT/2, NH, NB), 256 threads. Block x handles q-tiles x and NQT-1-x.
// Q pre-scaled by SCALE2 (log2-domain softmax). Defer-max: per-lane local max
// check + __all (no shfls); full shfl-max only in rescale branch. l kept as
// unreduced f32x4, reduced once per pass.
__global__ __launch_bounds__(256) void attn_kernel(const u16* __restrict__ Qg,
                                                   const u16* __restrict__ Kg,
                                                   const u16* __restrict__ Vtg,
                                                   const float* __restrict__ amask,
                                                   u16* __restrict__ Y) {
  __shared__ __align__(16) u16 Ks[2][64 * 128];
  __shared__ __align__(16) u16 Vt[2][128 * 64];
  __shared__ __align__(16) u16 Ps[4][16 * 72];
  const int tid = threadIdx.x, lane = tid & 63, wid = tid >> 6;
  const int g = lane >> 4, r = lane & 15;
  const int h = blockIdx.y, b = blockIdx.z;
  const int kh = h >> 2;
  const int qta = blockIdx.x, qtb = NQT - 1 - qta;

  const u16* Kbh = Kg + (long)(b * NKV + kh) * NT * HD;
  const u16* Vtbh = Vtg + (long)(b * NKV + kh) * HD * NT;  // [d][t]
  const u16* Qbh = Qg + (long)(b * NH + h) * NT * HD;
  const float* am_b = amask + b * NT;
  u16* Pw = &Ps[wid][0];

  const int total = qta + 1 + qtb + 1;  // == NQT + 1 == 33

  const int krow_l = lane >> 4;
  const int kchunk = lane & 15;
  auto stageK = [&](u16* dst, int kv0) {
#pragma unroll
    for (int ii = 0; ii < 4; ++ii) {
      int kvl = (wid * 4 + ii) * 4 + krow_l;
      const u16* src = Kbh + (long)(kv0 + kvl) * HD + ((kchunk ^ (kvl & 7)) * 8);
      gload16(src, dst + (wid * 4 + ii) * 512);
    }
  };
  const int vrow_l = lane >> 3;
  const int vchunk = lane & 7;
  auto stageVt = [&](u16* dst, int kv0) {
#pragma unroll
    for (int ii = 0; ii < 4; ++ii) {
      int d = (wid * 4 + ii) * 8 + vrow_l;
      const u16* src = Vtbh + (long)d * NT + kv0 + ((vchunk ^ (d & 7)) * 8);
      gload16(src, dst + (wid * 4 + ii) * 512);
    }
  };

  bf16x8 qf[4];
  auto loadQ = [&](int q0) {
    const u16* Qrow = Qbh + (long)(q0 + wid * 16 + r) * HD;
#pragma unroll
    for (int kc = 0; kc < 4; ++kc)
      qf[kc] = *(const bf16x8*)(Qrow + kc * 32 + 8 * g);
  };

  // ---- prologue ----
  stageK(Ks[0], 0);
  stageVt(Vt[0], 0);
  loadQ(qta * 64);
  __syncthreads();

  float m = -INFINITY;
  f32x4 lacc = {};
  f32x4 o[8] = {};
  int buf = 0;

  for (int i = 0; i < total; ++i) {
    const bool passA = (i <= qta);
    const int q0 = (passA ? qta : qtb) * 64;
    const int kt = passA ? i : i - qta - 1;
    const int kv0 = kt * 64;
    const bool diag = (i == qta) || (i == total - 1);
    const int qi = q0 + wid * 16 + r;

    if (i + 1 < total) {
      const int ktn = (i + 1 <= qta) ? i + 1 : i - qta;
      stageK(Ks[buf ^ 1], ktn * 64);
      stageVt(Vt[buf ^ 1], ktn * 64);
    }

    const u16* Ksb = Ks[buf];
    const u16* Vtb = Vt[buf];

    // ---- S^T = mfma(K, Q): lane owns S[q=qi][kv = kv0 + cb*16 + 4g + jj] ----
    f32x4 s[4];
    __builtin_amdgcn_s_setprio(1);
#pragma unroll
    for (int cb = 0; cb < 4; ++cb) {
      f32x4 acc = {};
      int row = cb * 16 + r;
      int swz = (r & 7) << 4;
#pragma unroll
      for (int kc = 0; kc < 4; ++kc) {
        bf16x8 kf = *(const bf16x8*)((const char*)Ksb + ((row * 256 + (kc * 32 + 8 * g) * 2) ^ swz));
        acc = __builtin_amdgcn_mfma_f32_16x16x32_bf16(kf, qf[kc], acc, 0, 0, 0);
      }
      s[cb] = acc;
    }
    __builtin_amdgcn_s_setprio(0);

    // ---- causal (diag tiles only); scores already log2-scaled via Q ----
    if (diag) {
#pragma unroll
      for (int cb = 0; cb < 4; ++cb)
#pragma unroll
        for (int jj = 0; jj < 4; ++jj) {
          int kvi = kv0 + cb * 16 + 4 * g + jj;
          if (kvi > qi) s[cb][jj] = -INFINITY;
        }
    }

    // ---- defer-max check: per-lane local max, wave-uniform decision, no shfls ----
    float mxl = s[0][0];
#pragma unroll
    for (int cb = 0; cb < 4; ++cb)
#pragma unroll
      for (int jj = 0; jj < 4; ++jj) mxl = fmaxf(mxl, s[cb][jj]);
    if (!__all(mxl <= m + 8.f)) {
      float mx = mxl;
      mx = fmaxf(mx, __shfl_xor(mx, 16));
      mx = fmaxf(mx, __shfl_xor(mx, 32));
      float mnew = fmaxf(m, mx);
      float alpha = exp2f(m - mnew);
      m = mnew;
      lacc[0] *= alpha; lacc[1] *= alpha; lacc[2] *= alpha; lacc[3] *= alpha;
#pragma unroll
      for (int nb = 0; nb < 8; ++nb) {
        o[nb][0] *= alpha; o[nb][1] *= alpha; o[nb][2] *= alpha; o[nb][3] *= alpha;
      }
    }

    float4 amv[4];
#pragma unroll
    for (int cb = 0; cb < 4; ++cb)
      amv[cb] = *(const float4*)(am_b + kv0 + cb * 16 + 4 * g);

    float p[4][4];
#pragma unroll
    for (int cb = 0; cb < 4; ++cb)
#pragma unroll
      for (int jj = 0; jj < 4; ++jj) {
        float pv = exp2f(s[cb][jj] - m) * (&amv[cb].x)[jj];
        p[cb][jj] = pv;
        lacc[jj] += pv;
      }

    // ---- P -> per-wave LDS (row q=r); __bf16 casts -> v_cvt_pk ----
#pragma unroll
    for (int cb = 0; cb < 4; ++cb) {
      union { __bf16 hh[4]; uint2 u; } pk;
      pk.hh[0] = (__bf16)p[cb][0]; pk.hh[1] = (__bf16)p[cb][1];
      pk.hh[2] = (__bf16)p[cb][2]; pk.hh[3] = (__bf16)p[cb][3];
      *(uint2*)((char*)Pw + 144 * r + 32 * cb + 8 * g) = pk.u;
    }
    asm volatile("s_waitcnt lgkmcnt(0)" ::: "memory");
    __builtin_amdgcn_sched_barrier(0);

    // ---- O^T += mfma(V^T, P): lane owns O[q=qi][d = nb*16 + 4g + jj] ----
    __builtin_amdgcn_s_setprio(1);
#pragma unroll
    for (int kc = 0; kc < 2; ++kc) {
      bf16x8 pb = *(const bf16x8*)((const char*)Pw + 144 * r + kc * 64 + 16 * g);
#pragma unroll
      for (int nb = 0; nb < 8; ++nb) {
        int d = nb * 16 + r;
        bf16x8 va = *(const bf16x8*)((const char*)Vtb +
            ((d * 128 + (kc * 32 + 8 * g) * 2) ^ ((d & 7) << 4)));
        o[nb] = __builtin_amdgcn_mfma_f32_16x16x32_bf16(va, pb, o[nb], 0, 0, 0);
      }
    }
    __builtin_amdgcn_s_setprio(0);

    // ---- pass epilogue: reduce l once, write Y ----
    if (diag) {
      float l = (lacc[0] + lacc[1]) + (lacc[2] + lacc[3]);
      l += __shfl_xor(l, 16);
      l += __shfl_xor(l, 32);
      float invl = 1.f / l;
      u16* Yrow = Y + ((long)b * NT + qi) * NC + h * HD;
#pragma unroll
      for (int nb = 0; nb < 8; ++nb)
        *(uint2*)(Yrow + nb * 16 + 4 * g) =
            make_uint2(packbf2(o[nb][0] * invl, o[nb][1] * invl),
                       packbf2(o[nb][2] * invl, o[nb][3] * invl));
      if (i == qta) {
        m = -INFINITY;
        lacc = f32x4{};
#pragma unroll
        for (int nb = 0; nb < 8; ++nb) o[nb] = f32x4{};
        loadQ(qtb * 64);
      }
    }

    __syncthreads();
    buf ^= 1;
  }
}

extern "C" void kernel_launch(void* const* d_in, const int* in_sizes, int n_in,
                              void* d_out, int out_size, void* d_ws, size_t ws_size,
                              hipStream_t stream) {
  const float* x = (const float*)d_in[0];
  const float* amask = (const float*)d_in[1];
  const float* w_qkv = (const float*)d_in[2];
  const float* w_proj = (const float*)d_in[3];

  const long MT = (long)NB * NT;  // 4096
  char* ws = (char*)d_ws;
  size_t off = 0;
  auto carve = [&](size_t bytes) -> char* {
    char* p = ws + off;
    off += (bytes + 255) & ~(size_t)255;
    return p;
  };
  u16* xb   = (u16*)carve((size_t)MT * NC * 2);       // A for gemm1; later Y
  u16* wqb  = (u16*)carve((size_t)NQKV * NC * 2);     // B for gemm1; later Vt
  u16* wpb  = (u16*)carve((size_t)NC * NC * 2);       // B for gemm2
  u16* Qb   = (u16*)carve((size_t)NB * NH * NT * HD * 2);
  u16* Kb   = (u16*)carve((size_t)NB * NKV * NT * HD * 2);
  u16* Vcb  = (u16*)carve((size_t)MT * NKV * HD * 2);
  float* tab = (float*)carve((size_t)NT * 128 * 4);

  u16* Vtb = wqb;   // overlay: written by vtrans after gemm1 is done with wqb
  u16* Yb  = xb;    // overlay: written by attn after gemm1 is done with xb

  {
    int n4 = (int)(MT * NC / 4);
    cvt_bf16_kernel<<<dim3((n4 + 255) / 256), dim3(256), 0, stream>>>(x, xb, n4);
    n4 = (int)((long)NQKV * NC / 4);
    cvt_wqkv_kernel<<<dim3((n4 + 255) / 256), dim3(256), 0, stream>>>(w_qkv, wqb, n4);
    n4 = (int)((long)NC * NC / 4);
    cvt_bf16_kernel<<<dim3((n4 + 255) / 256), dim3(256), 0, stream>>>(w_proj, wpb, n4);
  }
  rope_tab_kernel<<<dim3(NT * 64 / 256), dim3(256), 0, stream>>>(tab);
  gemm_bt_kernel<1><<<dim3(NQKV / 128, MT / 128), dim3(256), 0, stream>>>(
      xb, wqb, nullptr, (int)MT, NQKV, NC, tab, Qb, Kb, Vcb);
  vtrans_kernel<<<dim3(NT / 64 * 2, NB * NKV), dim3(256), 0, stream>>>(Vcb, Vtb);
  attn_kernel<<<dim3(NQT / 2, NH, NB), dim3(256), 0, stream>>>(Qb, Kb, Vtb, amask, Yb);
  gemm_bt_kernel<0><<<dim3(NC / 128, MT / 128), dim3(256), 0, stream>>>(
      Yb, wpb, d_out, (int)MT, NC, NC, nullptr, nullptr, nullptr, nullptr);
}

// Round 7
// 236.712 us; speedup vs baseline: 1.1031x; 1.1031x over previous
//
#include <hip/hip_runtime.h>
#include <hip/hip_bf16.h>
#include <stdint.h>

typedef unsigned short u16;
typedef __attribute__((ext_vector_type(4))) float f32x4;
typedef __attribute__((ext_vector_type(8))) __bf16 bf16x8;
typedef __attribute__((ext_vector_type(8))) unsigned short u16x8;

#define NB 2
#define NT 2048
#define NC 2048
#define NH 16
#define NKV 4
#define HD 128
#define NQKV 3072
#define NQT 32   // NT/64
#define SCALE2 0.12751739f  // (1/sqrt(128)) * log2(e)

__device__ __forceinline__ u16 f2bf(float f) {
  union { float f; uint32_t u; } c; c.f = f;
  uint32_t u = c.u + 0x7fffu + ((c.u >> 16) & 1u);
  return (u16)(u >> 16);
}
__device__ __forceinline__ float bf2f(u16 h) {
  union { uint32_t u; float f; } c; c.u = ((uint32_t)h) << 16;
  return c.f;
}
__device__ __forceinline__ uint32_t packbf2(float a, float b) {
  return (uint32_t)f2bf(a) | ((uint32_t)f2bf(b) << 16);
}

// global -> LDS async copy, 16B per lane. LDS dest = wave-uniform base + lane*16.
__device__ __forceinline__ void gload16(const void* g, void* lds) {
  __builtin_amdgcn_global_load_lds(
      (__attribute__((address_space(1))) void*)(uintptr_t)g,
      (__attribute__((address_space(3))) void*)(uint32_t)(uintptr_t)lds,
      16, 0, 0);
}

// ---------------- fp32 -> bf16 convert ----------------
__global__ void cvt_bf16_kernel(const float* __restrict__ in, u16* __restrict__ out, int n4) {
  int i = blockIdx.x * blockDim.x + threadIdx.x;
  if (i >= n4) return;
  float4 v = ((const float4*)in)[i];
  uint32_t lo = (uint32_t)f2bf(v.x) | ((uint32_t)f2bf(v.y) << 16);
  uint32_t hi = (uint32_t)f2bf(v.z) | ((uint32_t)f2bf(v.w) << 16);
  ((uint2*)out)[i] = make_uint2(lo, hi);
}

// ---------------- RoPE cos/sin table ----------------
__global__ void rope_tab_kernel(float* __restrict__ tab) {
  int idx = blockIdx.x * blockDim.x + threadIdx.x;  // NT*64
  int t = idx >> 6, i = idx & 63;
  float inv = expf(-(float)(2 * i) * (9.210340371976184f / 128.f));
  float f = (float)t * inv;
  tab[t * 128 + i] = cosf(f);
  tab[t * 128 + 64 + i] = sinf(f);
}

// ---------------- RoPE apply + head split/transpose (Q and K only) ----------------
// Q additionally pre-scaled by SCALE2 (log2-domain softmax happens in attn).
__global__ void rope_apply_kernel(const u16* __restrict__ qkv, const float* __restrict__ tab,
                                  u16* __restrict__ Q, u16* __restrict__ K) {
  int idx = blockIdx.x * blockDim.x + threadIdx.x;  // NB*NT*20*64
  int i = idx & 63;
  int rest = idx >> 6;
  int hh = rest % 20;
  int bt = rest / 20;
  int t = bt & (NT - 1);
  int b = bt >> 11;
  const u16* src_row = qkv + (long)bt * NQKV;
  float c = tab[t * 128 + i], s = tab[t * 128 + 64 + i];
  if (hh < NH) {
    const u16* sp = src_row + hh * HD;
    float x0 = bf2f(sp[i]), x1 = bf2f(sp[i + 64]);
    u16* dp = Q + ((long)(b * NH + hh) * NT + t) * HD;
    dp[i] = f2bf((x0 * c - x1 * s) * SCALE2);
    dp[i + 64] = f2bf((x1 * c + x0 * s) * SCALE2);
  } else {
    int kh = hh - NH;
    const u16* sp = src_row + (NH + kh) * HD;
    float x0 = bf2f(sp[i]), x1 = bf2f(sp[i + 64]);
    u16* dp = K + ((long)(b * NKV + kh) * NT + t) * HD;
    dp[i] = f2bf(x0 * c - x1 * s);
    dp[i + 64] = f2bf(x1 * c + x0 * s);
  }
}

// ---------------- V transpose: qkv[bt][2560 + kh*128 + d] -> Vt[b][kh][d][t] ----------------
__global__ void vtrans_kernel(const u16* __restrict__ qkv, u16* __restrict__ Vt) {
  __shared__ u16 tile[64][72];
  const int t0 = (blockIdx.x >> 1) * 64;
  const int d0 = (blockIdx.x & 1) * 64;
  const int bkh = blockIdx.y;                 // b*NKV + kh
  const int tid = threadIdx.x;
  const int tr = tid >> 2;
  const int tc = (tid & 3) * 16;
  const u16* src = qkv + ((long)((bkh >> 2) * NT) + t0 + tr) * NQKV +
                   (NH + NKV) * HD + (bkh & 3) * HD + d0 + tc;
  uint4 v0 = *(const uint4*)(src);
  uint4 v1 = *(const uint4*)(src + 8);
  *(uint4*)&tile[tr][tc] = v0;
  *(uint4*)&tile[tr][tc + 8] = v1;
  __syncthreads();
  const int dr = tid >> 2;
  const int tcc = (tid & 3) * 16;
  uint32_t pk[8];
#pragma unroll
  for (int e = 0; e < 8; ++e) {
    u16 a = tile[tcc + 2 * e][dr];
    u16 bq = tile[tcc + 2 * e + 1][dr];
    pk[e] = (uint32_t)a | ((uint32_t)bq << 16);
  }
  u16* dst = Vt + ((long)bkh * HD + d0 + dr) * NT + t0 + tcc;
  *(uint4*)(dst) = *(uint4*)&pk[0];
  *(uint4*)(dst + 8) = *(uint4*)&pk[4];
}

// ---------------- GEMM: C[M][N] = A[M][K] * B[N][K]^T ----------------
template <int OUT_BF16>
__global__ __launch_bounds__(256) void gemm_bt_kernel(const u16* __restrict__ A,
                                                      const u16* __restrict__ Bm,
                                                      void* __restrict__ Cm,
                                                      int M, int N, int K) {
  __shared__ __align__(16) u16 As[128 * 32];
  __shared__ __align__(16) u16 Bs[128 * 32];
  const int tid = threadIdx.x;
  const int lane = tid & 63;
  const int wid = tid >> 6;
  const long row0 = (long)blockIdx.y * 128;
  const long col0 = (long)blockIdx.x * 128;
  const int wr = (wid >> 1) * 64;
  const int wc = (wid & 1) * 64;
  const int g = lane >> 4;
  const int r = lane & 15;
  const int crow = lane >> 2;
  const int ccol = (lane & 3) * 8;
  const int c0 = wid * 2, c1 = wid * 2 + 1;

  f32x4 acc[4][4] = {};

  const u16* Abase0 = A + (row0 + c0 * 16 + crow) * (long)K + ccol;
  const u16* Abase1 = A + (row0 + c1 * 16 + crow) * (long)K + ccol;
  const u16* Bbase0 = Bm + (col0 + c0 * 16 + crow) * (long)K + ccol;
  const u16* Bbase1 = Bm + (col0 + c1 * 16 + crow) * (long)K + ccol;

  for (int k0 = 0; k0 < K; k0 += 32) {
    gload16(Abase0 + k0, &As[c0 * 512]);
    gload16(Abase1 + k0, &As[c1 * 512]);
    gload16(Bbase0 + k0, &Bs[c0 * 512]);
    gload16(Bbase1 + k0, &Bs[c1 * 512]);
    __syncthreads();
    bf16x8 af[4], bfr[4];
#pragma unroll
    for (int mi = 0; mi < 4; ++mi)
      af[mi] = *(const bf16x8*)&As[(wr + mi * 16 + r) * 32 + 8 * g];
#pragma unroll
    for (int ni = 0; ni < 4; ++ni)
      bfr[ni] = *(const bf16x8*)&Bs[(wc + ni * 16 + r) * 32 + 8 * g];
#pragma unroll
    for (int mi = 0; mi < 4; ++mi)
#pragma unroll
      for (int ni = 0; ni < 4; ++ni)
        acc[mi][ni] = __builtin_amdgcn_mfma_f32_16x16x32_bf16(af[mi], bfr[ni], acc[mi][ni], 0, 0, 0);
    __syncthreads();
  }
#pragma unroll
  for (int mi = 0; mi < 4; ++mi)
#pragma unroll
    for (int ni = 0; ni < 4; ++ni)
#pragma unroll
      for (int j = 0; j < 4; ++j) {
        long rr = row0 + wr + mi * 16 + g * 4 + j;
        long cc = col0 + wc + ni * 16 + r;
        float v = acc[mi][ni][j];
        if (OUT_BF16) ((u16*)Cm)[rr * N + cc] = f2bf(v);
        else          ((float*)Cm)[rr * N + cc] = v;
      }
}

// ---------------- Flash attention v5: shfl-free steady state ----------------
// Grid: (NQT/2, NH, NB), 256 threads. Block x handles q-tiles x and NQT-1-x.
// Q pre-scaled by SCALE2 (log2-domain softmax). Defer-max: per-lane local max
// check + __all (no shfls); full shfl-max only in rescale branch. l kept as
// unreduced f32x4, reduced once per pass.
__global__ __launch_bounds__(256) void attn_kernel(const u16* __restrict__ Qg,
                                                   const u16* __restrict__ Kg,
                                                   const u16* __restrict__ Vtg,
                                                   const float* __restrict__ amask,
                                                   u16* __restrict__ Y) {
  __shared__ __align__(16) u16 Ks[2][64 * 128];
  __shared__ __align__(16) u16 Vt[2][128 * 64];
  __shared__ __align__(16) u16 Ps[4][16 * 72];
  const int tid = threadIdx.x, lane = tid & 63, wid = tid >> 6;
  const int g = lane >> 4, r = lane & 15;
  const int h = blockIdx.y, b = blockIdx.z;
  const int kh = h >> 2;
  const int qta = blockIdx.x, qtb = NQT - 1 - qta;

  const u16* Kbh = Kg + (long)(b * NKV + kh) * NT * HD;
  const u16* Vtbh = Vtg + (long)(b * NKV + kh) * HD * NT;  // [d][t]
  const u16* Qbh = Qg + (long)(b * NH + h) * NT * HD;
  const float* am_b = amask + b * NT;
  u16* Pw = &Ps[wid][0];

  const int total = qta + 1 + qtb + 1;  // == NQT + 1 == 33

  const int krow_l = lane >> 4;
  const int kchunk = lane & 15;
  auto stageK = [&](u16* dst, int kv0) {
#pragma unroll
    for (int ii = 0; ii < 4; ++ii) {
      int kvl = (wid * 4 + ii) * 4 + krow_l;
      const u16* src = Kbh + (long)(kv0 + kvl) * HD + ((kchunk ^ (kvl & 7)) * 8);
      gload16(src, dst + (wid * 4 + ii) * 512);
    }
  };
  const int vrow_l = lane >> 3;
  const int vchunk = lane & 7;
  auto stageVt = [&](u16* dst, int kv0) {
#pragma unroll
    for (int ii = 0; ii < 4; ++ii) {
      int d = (wid * 4 + ii) * 8 + vrow_l;
      const u16* src = Vtbh + (long)d * NT + kv0 + ((vchunk ^ (d & 7)) * 8);
      gload16(src, dst + (wid * 4 + ii) * 512);
    }
  };

  bf16x8 qf[4];
  auto loadQ = [&](int q0) {
    const u16* Qrow = Qbh + (long)(q0 + wid * 16 + r) * HD;
#pragma unroll
    for (int kc = 0; kc < 4; ++kc)
      qf[kc] = *(const bf16x8*)(Qrow + kc * 32 + 8 * g);
  };

  // ---- prologue ----
  stageK(Ks[0], 0);
  stageVt(Vt[0], 0);
  loadQ(qta * 64);
  __syncthreads();

  float m = -INFINITY;
  f32x4 lacc = {};
  f32x4 o[8] = {};
  int buf = 0;

  for (int i = 0; i < total; ++i) {
    const bool passA = (i <= qta);
    const int q0 = (passA ? qta : qtb) * 64;
    const int kt = passA ? i : i - qta - 1;
    const int kv0 = kt * 64;
    const bool diag = (i == qta) || (i == total - 1);
    const int qi = q0 + wid * 16 + r;

    if (i + 1 < total) {
      const int ktn = (i + 1 <= qta) ? i + 1 : i - qta;
      stageK(Ks[buf ^ 1], ktn * 64);
      stageVt(Vt[buf ^ 1], ktn * 64);
    }

    const u16* Ksb = Ks[buf];
    const u16* Vtb = Vt[buf];

    // ---- S^T = mfma(K, Q): lane owns S[q=qi][kv = kv0 + cb*16 + 4g + jj] ----
    f32x4 s[4];
    __builtin_amdgcn_s_setprio(1);
#pragma unroll
    for (int cb = 0; cb < 4; ++cb) {
      f32x4 acc = {};
      int row = cb * 16 + r;
      int swz = (r & 7) << 4;
#pragma unroll
      for (int kc = 0; kc < 4; ++kc) {
        bf16x8 kf = *(const bf16x8*)((const char*)Ksb + ((row * 256 + (kc * 32 + 8 * g) * 2) ^ swz));
        acc = __builtin_amdgcn_mfma_f32_16x16x32_bf16(kf, qf[kc], acc, 0, 0, 0);
      }
      s[cb] = acc;
    }
    __builtin_amdgcn_s_setprio(0);

    // ---- causal (diag tiles only); scores already log2-scaled via Q ----
    if (diag) {
#pragma unroll
      for (int cb = 0; cb < 4; ++cb)
#pragma unroll
        for (int jj = 0; jj < 4; ++jj) {
          int kvi = kv0 + cb * 16 + 4 * g + jj;
          if (kvi > qi) s[cb][jj] = -INFINITY;
        }
    }

    // ---- defer-max check: per-lane local max, wave-uniform decision, no shfls ----
    float mxl = s[0][0];
#pragma unroll
    for (int cb = 0; cb < 4; ++cb)
#pragma unroll
      for (int jj = 0; jj < 4; ++jj) mxl = fmaxf(mxl, s[cb][jj]);
    if (!__all(mxl <= m + 8.f)) {
      float mx = mxl;
      mx = fmaxf(mx, __shfl_xor(mx, 16));
      mx = fmaxf(mx, __shfl_xor(mx, 32));
      float mnew = fmaxf(m, mx);
      float alpha = exp2f(m - mnew);
      m = mnew;
      lacc[0] *= alpha; lacc[1] *= alpha; lacc[2] *= alpha; lacc[3] *= alpha;
#pragma unroll
      for (int nb = 0; nb < 8; ++nb) {
        o[nb][0] *= alpha; o[nb][1] *= alpha; o[nb][2] *= alpha; o[nb][3] *= alpha;
      }
    }

    float4 amv[4];
#pragma unroll
    for (int cb = 0; cb < 4; ++cb)
      amv[cb] = *(const float4*)(am_b + kv0 + cb * 16 + 4 * g);

    float p[4][4];
#pragma unroll
    for (int cb = 0; cb < 4; ++cb)
#pragma unroll
      for (int jj = 0; jj < 4; ++jj) {
        float pv = exp2f(s[cb][jj] - m) * (&amv[cb].x)[jj];
        p[cb][jj] = pv;
        lacc[jj] += pv;
      }

    // ---- P -> per-wave LDS (row q=r); __bf16 casts -> v_cvt_pk ----
#pragma unroll
    for (int cb = 0; cb < 4; ++cb) {
      union { __bf16 hh[4]; uint2 u; } pk;
      pk.hh[0] = (__bf16)p[cb][0]; pk.hh[1] = (__bf16)p[cb][1];
      pk.hh[2] = (__bf16)p[cb][2]; pk.hh[3] = (__bf16)p[cb][3];
      *(uint2*)((char*)Pw + 144 * r + 32 * cb + 8 * g) = pk.u;
    }
    asm volatile("s_waitcnt lgkmcnt(0)" ::: "memory");
    __builtin_amdgcn_sched_barrier(0);

    // ---- O^T += mfma(V^T, P): lane owns O[q=qi][d = nb*16 + 4g + jj] ----
    __builtin_amdgcn_s_setprio(1);
#pragma unroll
    for (int kc = 0; kc < 2; ++kc) {
      bf16x8 pb = *(const bf16x8*)((const char*)Pw + 144 * r + kc * 64 + 16 * g);
#pragma unroll
      for (int nb = 0; nb < 8; ++nb) {
        int d = nb * 16 + r;
        bf16x8 va = *(const bf16x8*)((const char*)Vtb +
            ((d * 128 + (kc * 32 + 8 * g) * 2) ^ ((d & 7) << 4)));
        o[nb] = __builtin_amdgcn_mfma_f32_16x16x32_bf16(va, pb, o[nb], 0, 0, 0);
      }
    }
    __builtin_amdgcn_s_setprio(0);

    // ---- pass epilogue: reduce l once, write Y ----
    if (diag) {
      float l = (lacc[0] + lacc[1]) + (lacc[2] + lacc[3]);
      l += __shfl_xor(l, 16);
      l += __shfl_xor(l, 32);
      float invl = 1.f / l;
      u16* Yrow = Y + ((long)b * NT + qi) * NC + h * HD;
#pragma unroll
      for (int nb = 0; nb < 8; ++nb)
        *(uint2*)(Yrow + nb * 16 + 4 * g) =
            make_uint2(packbf2(o[nb][0] * invl, o[nb][1] * invl),
                       packbf2(o[nb][2] * invl, o[nb][3] * invl));
      if (i == qta) {
        m = -INFINITY;
        lacc = f32x4{};
#pragma unroll
        for (int nb = 0; nb < 8; ++nb) o[nb] = f32x4{};
        loadQ(qtb * 64);
      }
    }

    __syncthreads();
    buf ^= 1;
  }
}

extern "C" void kernel_launch(void* const* d_in, const int* in_sizes, int n_in,
                              void* d_out, int out_size, void* d_ws, size_t ws_size,
                              hipStream_t stream) {
  const float* x = (const float*)d_in[0];
  const float* amask = (const float*)d_in[1];
  const float* w_qkv = (const float*)d_in[2];
  const float* w_proj = (const float*)d_in[3];

  const long MT = (long)NB * NT;  // 4096
  char* ws = (char*)d_ws;
  size_t off = 0;
  auto carve = [&](size_t bytes) -> char* {
    char* p = ws + off;
    off += (bytes + 255) & ~(size_t)255;
    return p;
  };
  u16* xb   = (u16*)carve((size_t)MT * NC * 2);       // A for gemm1; later Q
  u16* wqb  = (u16*)carve((size_t)NQKV * NC * 2);     // B for gemm1; later K + Vt
  u16* wpb  = (u16*)carve((size_t)NC * NC * 2);       // B for gemm2
  u16* qkvb = (u16*)carve((size_t)MT * NQKV * 2);     // C of gemm1; later Y
  float* tab = (float*)carve((size_t)NT * 128 * 4);

  u16* Qb = xb;
  u16* Kb = wqb;
  u16* Vtb = wqb + (size_t)NB * NKV * NT * HD;
  u16* Yb = qkvb;

  {
    int n4 = (int)(MT * NC / 4);
    cvt_bf16_kernel<<<dim3((n4 + 255) / 256), dim3(256), 0, stream>>>(x, xb, n4);
    n4 = (int)((long)NQKV * NC / 4);
    cvt_bf16_kernel<<<dim3((n4 + 255) / 256), dim3(256), 0, stream>>>(w_qkv, wqb, n4);
    n4 = (int)((long)NC * NC / 4);
    cvt_bf16_kernel<<<dim3((n4 + 255) / 256), dim3(256), 0, stream>>>(w_proj, wpb, n4);
  }
  rope_tab_kernel<<<dim3(NT * 64 / 256), dim3(256), 0, stream>>>(tab);
  gemm_bt_kernel<1><<<dim3(NQKV / 128, MT / 128), dim3(256), 0, stream>>>(xb, wqb, qkvb, (int)MT, NQKV, NC);
  rope_apply_kernel<<<dim3(NB * NT * 20 * 64 / 256), dim3(256), 0, stream>>>(qkvb, tab, Qb, Kb);
  vtrans_kernel<<<dim3(NT / 64 * 2, NB * NKV), dim3(256), 0, stream>>>(qkvb, Vtb);
  attn_kernel<<<dim3(NQT / 2, NH, NB), dim3(256), 0, stream>>>(Qb, Kb, Vtb, amask, Yb);
  gemm_bt_kernel<0><<<dim3(NC / 128, MT / 128), dim3(256), 0, stream>>>(Yb, wpb, d_out, (int)MT, NC, NC);
}